// Round 13
// baseline (123.362 us; speedup 1.0000x reference)
//
#include <hip/hip_runtime.h>

typedef __attribute__((ext_vector_type(8))) short short8;
typedef __attribute__((ext_vector_type(8))) __bf16 bf16x8;
typedef __attribute__((ext_vector_type(4))) float f32x4;

// sizes
#define B_ 4
#define C_ 64
#define H_ 128
#define W_ 128
#define P_ (H_*W_)      // 16384
#define E_ 16

// ws layout (bytes)
#define OFF_XT   0u
#define XT_BYTES (4u*130u*130u*64u*2u)          // 8,652,800
#define OFF_A    8652800u
#define OFF_R1   9832448u
#define OFF_PARA 14026752u

__device__ inline unsigned short f2bf(float f) {
    union { float f; unsigned u; } v; v.f = f;
    unsigned r = v.u + 0x7FFF + ((v.u >> 16) & 1);
    return (unsigned short)(r >> 16);
}

// ---------- transpose+pad x -> xt bf16, FUSED with conv1x1+relu -> r1 ----------
__global__ __launch_bounds__(128) void k_transpose(const float* __restrict__ x,
                                                   unsigned short* __restrict__ xt,
                                                   const float* __restrict__ pw,
                                                   const float* __restrict__ pb,
                                                   float* __restrict__ r1) {
    __shared__ float lpw[1024];
    __shared__ float lpb[16];
    int b = blockIdx.x >> 7, y = blockIdx.x & 127;
    int t = threadIdx.x; // x coordinate
    for (int lin = t; lin < 1024; lin += 128) lpw[lin] = pw[lin];
    if (t < 16) lpb[t] = pb[t];
    __syncthreads();

    const float* src = x + (size_t)b * C_ * P_ + y * W_ + t;
    unsigned short* dst = xt + ((size_t)(b * 130 + y + 1) * 130 + t + 1) * 64;
    float s[16];
#pragma unroll
    for (int e = 0; e < 16; ++e) s[e] = lpb[e];
#pragma unroll
    for (int i = 0; i < 8; ++i) {
        short8 v;
#pragma unroll
        for (int j = 0; j < 8; ++j) {
            float xv = src[(size_t)(i * 8 + j) * P_];
            v[j] = (short)f2bf(xv);
#pragma unroll
            for (int e = 0; e < 16; ++e) s[e] = fmaf(lpw[e * 64 + i * 8 + j], xv, s[e]);
        }
        ((short8*)dst)[i] = v;
    }
    float* rd = r1 + (size_t)b * 16 * P_ + y * 128 + t;
#pragma unroll
    for (int e = 0; e < 16; ++e) rd[(size_t)e * P_] = fmaxf(s[e], 0.f);

    short8 z = {0,0,0,0,0,0,0,0};
    if (t < 16) {
        int col = (t >> 3) * 129, i = t & 7;
        unsigned short* bp = xt + ((size_t)(b * 130 + y + 1) * 130 + col) * 64;
        ((short8*)bp)[i] = z;
    }
    if (y == 0 || y == 127) {
        int prow = (y == 0) ? 0 : 129;
        unsigned short* rp = xt + (size_t)(b * 130 + prow) * 130 * 64;
        for (int ci = t; ci < 1040; ci += 128) ((short8*)rp)[ci] = z;
    }
}

// ---------- build A3 (fragment-linear) from W ----------
// A3 element offset = (g*72 + ks*4 + f)*512 + lane*8 + j   (g = o>>2, f = o&3)
// value = A_orig[row = o*16 + llo][col = ks*32 + lhi*8 + j], col = tap*64 + c
__global__ __launch_bounds__(256) void k_prepA(const float* __restrict__ Wsrc,
                                               unsigned short* __restrict__ A) {
    __shared__ float lw[9216];
    int o = blockIdx.x, t = threadIdx.x;
    const float* src = Wsrc + (size_t)o * 9216; // per o: [j'=c*9+tap][e]
    for (int lin = t; lin < 9216; lin += 256) lw[lin] = src[lin];
    __syncthreads();
    int g = o >> 2, f = o & 3;
    unsigned short* dst = A + ((size_t)g * 72 + f) * 512;
    for (int lin = t; lin < 9216; lin += 256) {
        int ks = lin >> 9, rem = lin & 511;
        int lane = rem >> 3, j = rem & 7;
        int llo = lane & 15, lhi = lane >> 4;
        int col = ks * 32 + lhi * 8 + j;
        int tap = col >> 6, c = col & 63;
        dst[(size_t)ks * 2048 + rem] = f2bf(lw[(c * 9 + tap) * 16 + llo]);
    }
}

// ---------- predictor conv3x3 -> para[b][e][p] f32 ----------
__global__ __launch_bounds__(256) void k_pred2(const float* __restrict__ r1,
                                               const float* __restrict__ cw,
                                               const float* __restrict__ cb,
                                               float* __restrict__ para) {
    __shared__ float lcw[2304];
    __shared__ float lcb[16];
    int t = threadIdx.x;
    for (int lin = t; lin < 2304; lin += 256) lcw[lin] = cw[lin];
    if (t < 16) lcb[t] = cb[t];
    __syncthreads();
    int gp = blockIdx.x * 256 + t;
    int b = gp >> 14, p = gp & 16383;
    int y = p >> 7, xc = p & 127;
    const float* rs = r1 + (size_t)b * 16 * P_;
    float s[16];
#pragma unroll
    for (int e = 0; e < 16; ++e) s[e] = lcb[e];
    for (int dy = 0; dy < 3; ++dy) {
        int yy = y + dy - 1;
        if (yy < 0 || yy > 127) continue;
        for (int dx = 0; dx < 3; ++dx) {
            int xv = xc + dx - 1;
            if (xv < 0 || xv > 127) continue;
            int q = yy * 128 + xv;
            int tap = dy * 3 + dx;
#pragma unroll
            for (int ep = 0; ep < 16; ++ep) {
                float v = rs[(size_t)ep * P_ + q];
#pragma unroll
                for (int e = 0; e < 16; ++e)
                    s[e] = fmaf(lcw[(e * 16 + ep) * 9 + tap], v, s[e]);
            }
        }
    }
    float* d = para + (size_t)b * 16 * P_ + p;
#pragma unroll
    for (int e = 0; e < 16; ++e) d[(size_t)e * P_] = s[e];
}

// ---------- main fused kernel ----------
// R13: waves split PIXELS, not o's. 256 threads (4 waves), one image row.
// Wave = 32 px (2 pg); chunk = 4 o's; 16 chunks cover all 64 o's; all waves
// walk the SAME chunk sequence -> af addresses identical across waves (L1
// broadcast), paced by a raw per-chunk s_barrier (no data crosses it).
// Block LDS reads drop 2.3MB -> 576KB (each wave reads only its 2 pg).
// acc[4][2] = 32 AGPRs; pvv (8 vals) hoisted out of the chunk loop.
__global__ __launch_bounds__(256, 2) void k_main(const unsigned short* __restrict__ xt,
                                                 const unsigned short* __restrict__ A,
                                                 const float* __restrict__ para,
                                                 float* __restrict__ out) {
    __shared__ unsigned short lds[3 * 130 * 64]; // 49,920 B
    int r = blockIdx.x;
    int xcd = r & 7;
    int yl = r >> 3;            // [0,64)
    int rowid = xcd * 64 + yl;  // contiguous 64-row slab per XCD (A stays L2-resident)
    int b = rowid >> 7, y = rowid & 127;

    int tid = threadIdx.x;
    int wave = tid >> 6, lane = tid & 63, lhi = lane >> 4, llo = lane & 15;

    // stage 3 padded xt rows (y..y+2), swizzle byte ^= ((xx&7)<<4)
    const unsigned short* xrow = xt + (size_t)(b * 130 + y) * 130 * 64;
    for (int ci = tid; ci < 3120; ci += 256) {
        int row = ci / 1040, rem = ci - row * 1040;
        int xx = rem >> 3, cc = rem & 7;
        short8 v = *(const short8*)(xrow + ((size_t)row * 130 + xx) * 64 + cc * 8);
        int lb = row * 16640 + xx * 128 + ((cc * 16) ^ ((xx & 7) << 4));
        *(short8*)((char*)lds + lb) = v;
    }
    __syncthreads();

    const float* pp = para + (size_t)b * 16 * P_ + y * 128 + wave * 32;
    float* po = out + (size_t)b * 64 * P_ + y * 128 + wave * 32;

    // LDS vaddrs for pgl=0 (pgl=1 is +2048): qv[parity][kw]
    int qv[2][3];
#pragma unroll
    for (int kw = 0; kw < 3; ++kw) {
        int rowi = wave * 32 + llo + kw;
        int base0 = rowi * 128 + ((lhi * 16) ^ ((rowi & 7) << 4));
        qv[0][kw] = base0;
        qv[1][kw] = base0 ^ 64;
    }
    const char* ldsc = (const char*)lds;

    // para values (chunk-invariant): e = lhi*4+rr, px = pgl*16+llo
    float pvv[2][4];
#pragma unroll
    for (int pgl = 0; pgl < 2; ++pgl)
#pragma unroll
        for (int rr = 0; rr < 4; ++rr)
            pvv[pgl][rr] = pp[(size_t)(lhi * 4 + rr) * P_ + pgl * 16 + llo];

#define PF_AF(dst, KS) do { \
    _Pragma("unroll") \
    for (int f_ = 0; f_ < 4; ++f_) \
        dst[f_] = *(const bf16x8*)(Agl + (KS) * 2048 + f_ * 512); \
    __builtin_amdgcn_sched_barrier(0); \
} while (0)

#define PF_BF(d0, d1, ADDR) do { \
    const char* bp_ = (ADDR); \
    d0 = *(const bf16x8*)bp_; \
    d1 = *(const bf16x8*)(bp_ + 2048); \
} while (0)

#define MFMA8(afU, b0, b1) do { \
    __builtin_amdgcn_s_setprio(1); \
    _Pragma("unroll") \
    for (int f_ = 0; f_ < 4; ++f_) { \
        acc[f_][0] = __builtin_amdgcn_mfma_f32_16x16x32_bf16(afU[f_], b0, acc[f_][0], 0, 0, 0); \
        acc[f_][1] = __builtin_amdgcn_mfma_f32_16x16x32_bf16(afU[f_], b1, acc[f_][1], 0, 0, 0); \
    } \
    __builtin_amdgcn_s_setprio(0); \
} while (0)

#pragma unroll 1
    for (int chunk = 0; chunk < 16; ++chunk) {
        // pacing barrier: keeps the 4 waves' shared af lines L1-resident.
        // No data is exchanged across it (each wave owns its px range).
        __builtin_amdgcn_s_barrier();

        const unsigned short* Agl = A + (size_t)chunk * 36864 + lane * 8;

        f32x4 acc[4][2];
#pragma unroll
        for (int f = 0; f < 4; ++f) {
            acc[f][0] = (f32x4){0.f, 0.f, 0.f, 0.f};
            acc[f][1] = (f32x4){0.f, 0.f, 0.f, 0.f};
        }

        bf16x8 afA[4], afB[4], bA0, bA1, bB0, bB1;
        PF_AF(afA, 0);
        PF_BF(bA0, bA1, ldsc + qv[0][0]);

#pragma unroll 1
        for (int kh = 0; kh < 3; ++kh) {
            const int ksc = kh * 6;
            const char* bprow = ldsc + kh * 16640;
            // t0 (ks=ksc: par0,kw0) -- prefetch ksc+1
            PF_AF(afB, ksc + 1); PF_BF(bB0, bB1, bprow + qv[1][0]); MFMA8(afA, bA0, bA1);
            // t1 (ksc+1: par1,kw0) -- prefetch ksc+2
            PF_AF(afA, ksc + 2); PF_BF(bA0, bA1, bprow + qv[0][1]); MFMA8(afB, bB0, bB1);
            // t2 (ksc+2: par0,kw1) -- prefetch ksc+3
            PF_AF(afB, ksc + 3); PF_BF(bB0, bB1, bprow + qv[1][1]); MFMA8(afA, bA0, bA1);
            // t3 (ksc+3: par1,kw1) -- prefetch ksc+4
            PF_AF(afA, ksc + 4); PF_BF(bA0, bA1, bprow + qv[0][2]); MFMA8(afB, bB0, bB1);
            // t4 (ksc+4: par0,kw2) -- prefetch ksc+5
            PF_AF(afB, ksc + 5); PF_BF(bB0, bB1, bprow + qv[1][2]); MFMA8(afA, bA0, bA1);
            // t5 (ksc+5: par1,kw2) -- prefetch next kh's (kw0,par0)
            PF_AF(afA, ksc + 6); // ks=18 overread at kh=2: lands in r1 region, never consumed
            if (kh < 2) PF_BF(bA0, bA1, bprow + 16640 + qv[0][0]);
            MFMA8(afB, bB0, bB1);
        }

        // epilogue: multiply rows (e) by para[e,p], reduce over e
#pragma unroll
        for (int f = 0; f < 4; ++f) {
            int o = chunk * 4 + f;
#pragma unroll
            for (int pgl = 0; pgl < 2; ++pgl) {
                float s = acc[f][pgl][0] * pvv[pgl][0] + acc[f][pgl][1] * pvv[pgl][1] +
                          acc[f][pgl][2] * pvv[pgl][2] + acc[f][pgl][3] * pvv[pgl][3];
                s += __shfl_xor(s, 16);
                s += __shfl_xor(s, 32);
                if (lhi == 0)
                    __builtin_nontemporal_store(s, &po[(size_t)o * P_ + pgl * 16 + llo]);
            }
        }
    }
#undef PF_AF
#undef PF_BF
#undef MFMA8
}

extern "C" void kernel_launch(void* const* d_in, const int* in_sizes, int n_in,
                              void* d_out, int out_size, void* d_ws, size_t ws_size,
                              hipStream_t stream) {
    const float* x  = (const float*)d_in[0];
    const float* W  = (const float*)d_in[1];
    const float* pw = (const float*)d_in[2];
    const float* pb = (const float*)d_in[3];
    const float* cw = (const float*)d_in[4];
    const float* cb = (const float*)d_in[5];
    float* out = (float*)d_out;
    char* ws = (char*)d_ws;
    unsigned short* xt = (unsigned short*)(ws + OFF_XT);
    unsigned short* Am = (unsigned short*)(ws + OFF_A);
    float* r1   = (float*)(ws + OFF_R1);
    float* para = (float*)(ws + OFF_PARA);

    hipLaunchKernelGGL(k_transpose, dim3(B_ * H_), dim3(128), 0, stream, x, xt, pw, pb, r1);
    hipLaunchKernelGGL(k_prepA, dim3(64), dim3(256), 0, stream, W, Am);
    hipLaunchKernelGGL(k_pred2, dim3(B_ * P_ / 256), dim3(256), 0, stream, r1, cw, cb, para);
    hipLaunchKernelGGL(k_main, dim3(512), dim3(256), 0, stream, xt, Am, para, out);
}

// Round 14
// 110.389 us; speedup vs baseline: 1.1175x; 1.1175x over previous
//
#include <hip/hip_runtime.h>

typedef __attribute__((ext_vector_type(8))) short short8;
typedef __attribute__((ext_vector_type(8))) __bf16 bf16x8;
typedef __attribute__((ext_vector_type(4))) float f32x4;

// sizes
#define B_ 4
#define C_ 64
#define H_ 128
#define W_ 128
#define P_ (H_*W_)      // 16384
#define E_ 16

// ws layout (bytes)
#define OFF_XT   0u
#define XT_BYTES (4u*130u*130u*64u*2u)          // 8,652,800
#define OFF_A    8652800u
#define OFF_R1   9832448u
#define OFF_PARA 14026752u

__device__ inline unsigned short f2bf(float f) {
    union { float f; unsigned u; } v; v.f = f;
    unsigned r = v.u + 0x7FFF + ((v.u >> 16) & 1);
    return (unsigned short)(r >> 16);
}

// ---------- merged prep kernel: transpose+pad+conv1x1 (blocks 0..255, 2 rows
// each) and A3 build (blocks 256..319). Saves one launch. ----------
__global__ __launch_bounds__(256) void k_prep(const float* __restrict__ x,
                                              unsigned short* __restrict__ xt,
                                              const float* __restrict__ pw,
                                              const float* __restrict__ pb,
                                              float* __restrict__ r1,
                                              const float* __restrict__ Wsrc,
                                              unsigned short* __restrict__ A) {
    __shared__ float smem[9216];
    int t = threadIdx.x;
    if (blockIdx.x < 256) {
        // ---- transpose + pad + conv1x1+relu, two image rows per block ----
        float* lpw = smem;          // [1024]
        float* lpb = smem + 1024;   // [16]
        for (int lin = t; lin < 1024; lin += 256) lpw[lin] = pw[lin];
        if (t < 16) lpb[t] = pb[t];
        __syncthreads();

        int rowid = blockIdx.x * 2 + (t >> 7);
        int b = rowid >> 7, y = rowid & 127;
        int tt = t & 127; // x coordinate

        const float* src = x + (size_t)b * C_ * P_ + y * W_ + tt;
        unsigned short* dst = xt + ((size_t)(b * 130 + y + 1) * 130 + tt + 1) * 64;
        float s[16];
#pragma unroll
        for (int e = 0; e < 16; ++e) s[e] = lpb[e];
#pragma unroll
        for (int i = 0; i < 8; ++i) {
            short8 v;
#pragma unroll
            for (int j = 0; j < 8; ++j) {
                float xv = src[(size_t)(i * 8 + j) * P_];
                v[j] = (short)f2bf(xv);
#pragma unroll
                for (int e = 0; e < 16; ++e) s[e] = fmaf(lpw[e * 64 + i * 8 + j], xv, s[e]);
            }
            ((short8*)dst)[i] = v;
        }
        float* rd = r1 + (size_t)b * 16 * P_ + y * 128 + tt;
#pragma unroll
        for (int e = 0; e < 16; ++e) rd[(size_t)e * P_] = fmaxf(s[e], 0.f);

        short8 z = {0,0,0,0,0,0,0,0};
        if (tt < 16) {
            int col = (tt >> 3) * 129, i = tt & 7;
            unsigned short* bp = xt + ((size_t)(b * 130 + y + 1) * 130 + col) * 64;
            ((short8*)bp)[i] = z;
        }
        if (y == 0 || y == 127) {
            int prow = (y == 0) ? 0 : 129;
            unsigned short* rp = xt + (size_t)(b * 130 + prow) * 130 * 64;
            for (int ci = tt; ci < 1040; ci += 128) ((short8*)rp)[ci] = z;
        }
    } else {
        // ---- A3 build: o = blockIdx - 256 ----
        // A3 elem offset = (g*72 + ks*4 + f)*512 + lane*8 + j (g=o>>2, f=o&3)
        // value = A_orig[row=o*16+llo][col=ks*32+lhi*8+j], col = tap*64 + c
        int o = blockIdx.x - 256;
        const float* src = Wsrc + (size_t)o * 9216; // per o: [j'=c*9+tap][e]
        for (int lin = t; lin < 9216; lin += 256) smem[lin] = src[lin];
        __syncthreads();
        int g = o >> 2, f = o & 3;
        unsigned short* dst = A + ((size_t)g * 72 + f) * 512;
        for (int lin = t; lin < 9216; lin += 256) {
            int ks = lin >> 9, rem = lin & 511;
            int lane = rem >> 3, j = rem & 7;
            int llo = lane & 15, lhi = lane >> 4;
            int col = ks * 32 + lhi * 8 + j;
            int tap = col >> 6, c = col & 63;
            dst[(size_t)ks * 2048 + rem] = f2bf(smem[(c * 9 + tap) * 16 + llo]);
        }
    }
}

// ---------- predictor conv3x3 -> para[b][e][p] f32 ----------
__global__ __launch_bounds__(256) void k_pred2(const float* __restrict__ r1,
                                               const float* __restrict__ cw,
                                               const float* __restrict__ cb,
                                               float* __restrict__ para) {
    __shared__ float lcw[2304];
    __shared__ float lcb[16];
    int t = threadIdx.x;
    for (int lin = t; lin < 2304; lin += 256) lcw[lin] = cw[lin];
    if (t < 16) lcb[t] = cb[t];
    __syncthreads();
    int gp = blockIdx.x * 256 + t;
    int b = gp >> 14, p = gp & 16383;
    int y = p >> 7, xc = p & 127;
    const float* rs = r1 + (size_t)b * 16 * P_;
    float s[16];
#pragma unroll
    for (int e = 0; e < 16; ++e) s[e] = lcb[e];
    for (int dy = 0; dy < 3; ++dy) {
        int yy = y + dy - 1;
        if (yy < 0 || yy > 127) continue;
        for (int dx = 0; dx < 3; ++dx) {
            int xv = xc + dx - 1;
            if (xv < 0 || xv > 127) continue;
            int q = yy * 128 + xv;
            int tap = dy * 3 + dx;
#pragma unroll
            for (int ep = 0; ep < 16; ++ep) {
                float v = rs[(size_t)ep * P_ + q];
#pragma unroll
                for (int e = 0; e < 16; ++e)
                    s[e] = fmaf(lcw[(e * 16 + ep) * 9 + tap], v, s[e]);
            }
        }
    }
    float* d = para + (size_t)b * 16 * P_ + p;
#pragma unroll
    for (int e = 0; e < 16; ++e) d[(size_t)e * P_] = s[e];
}

// ---------- main fused kernel ----------
// R14: R12 body (fragment-linear A3 af double-buffer, setprio, 16 MFMA : 8
// loads per body) at HALF the register footprint -> 3 waves/SIMD.
// Block = 64 px (half row), 256 threads, 4 waves; wave owns 16 o's
// (4 chunks x 4 f) x 64 px: acc[4][4] = 64 AGPR, ~100 VGPR => ~164 total,
// 3 blocks/CU (LDS 49.9KB caps at 3 too). Grid 1024, XCD-pinned.
__global__ __launch_bounds__(256, 2) void k_main(const unsigned short* __restrict__ xt,
                                                 const unsigned short* __restrict__ A,
                                                 const float* __restrict__ para,
                                                 float* __restrict__ out) {
    __shared__ unsigned short lds[3 * 130 * 64]; // 49,920 B
    int r = blockIdx.x;
    int xcd = r & 7;
    int ord = r >> 3;           // [0,128)
    int half = ord & 1;         // which 64-px half of the row
    int yl = ord >> 1;          // [0,64)
    int rowid = xcd * 64 + yl;  // contiguous 64-row slab per XCD (A stays L2-resident)
    int b = rowid >> 7, y = rowid & 127;

    int tid = threadIdx.x;
    int wave = tid >> 6, lane = tid & 63, lhi = lane >> 4, llo = lane & 15;

    // stage 3 padded xt rows (y..y+2), swizzle byte ^= ((xx&7)<<4)
    const unsigned short* xrow = xt + (size_t)(b * 130 + y) * 130 * 64;
    for (int ci = tid; ci < 3120; ci += 256) {
        int row = ci / 1040, rem = ci - row * 1040;
        int xx = rem >> 3, cc = rem & 7;
        short8 v = *(const short8*)(xrow + ((size_t)row * 130 + xx) * 64 + cc * 8);
        int lb = row * 16640 + xx * 128 + ((cc * 16) ^ ((xx & 7) << 4));
        *(short8*)((char*)lds + lb) = v;
    }
    __syncthreads();

    const float* pp = para + (size_t)b * 16 * P_ + y * 128 + half * 64;
    float* po = out + (size_t)b * 64 * P_ + y * 128 + half * 64;

    // precomputed LDS read vaddrs: qv[parity][kw]; full addr = qv + kh*16640 + pg*2048
    int qv[2][3];
#pragma unroll
    for (int kw = 0; kw < 3; ++kw) {
        int rowi = half * 64 + llo + kw;
        int base0 = rowi * 128 + ((lhi * 16) ^ ((rowi & 7) << 4));
        qv[0][kw] = base0;
        qv[1][kw] = base0 ^ 64;
    }
    const char* ldsc = (const char*)lds;

    // para values (chunk-invariant): e = lhi*4+rr, px = pg*16+llo
    float pvv[4][4];
#pragma unroll
    for (int pg = 0; pg < 4; ++pg)
#pragma unroll
        for (int rr = 0; rr < 4; ++rr)
            pvv[pg][rr] = pp[(size_t)(lhi * 4 + rr) * P_ + pg * 16 + llo];

#define PF_AF(dst, KS) do { \
    _Pragma("unroll") \
    for (int f_ = 0; f_ < 4; ++f_) \
        dst[f_] = *(const bf16x8*)(Agl + (KS) * 2048 + f_ * 512); \
    __builtin_amdgcn_sched_barrier(0); \
} while (0)

#pragma unroll 1
    for (int chunk = 0; chunk < 4; ++chunk) {
        int obase = chunk * 16 + wave * 4;
        int g = obase >> 2; // o-group index into A3 (= chunk*4 + wave)
        const unsigned short* Agl = A + (size_t)g * 36864 + lane * 8;

        f32x4 acc[4][4];
#pragma unroll
        for (int f = 0; f < 4; ++f)
#pragma unroll
            for (int pg = 0; pg < 4; ++pg) acc[f][pg] = (f32x4){0.f, 0.f, 0.f, 0.f};

        bf16x8 afA[4], afB[4];
        // prologue: A-frags for ks=0
        PF_AF(afA, 0);

#pragma unroll 1
        for (int kh = 0; kh < 3; ++kh) {
#pragma unroll 1
            for (int kw = 0; kw < 3; ++kw) {
                const int ksc = kh * 6 + kw * 2; // current even ks
                const char* bprow = ldsc + kh * 16640;
                // ---- half 0 (parity 0): compute with afA, prefetch ksc+1 -> afB
                {
                    PF_AF(afB, ksc + 1);
                    const char* bp = bprow + qv[0][kw];
                    bf16x8 bf[4];
#pragma unroll
                    for (int pg = 0; pg < 4; ++pg)
                        bf[pg] = *(const bf16x8*)(bp + pg * 2048);
                    __builtin_amdgcn_s_setprio(1);
#pragma unroll
                    for (int f = 0; f < 4; ++f)
#pragma unroll
                        for (int pg = 0; pg < 4; ++pg)
                            acc[f][pg] = __builtin_amdgcn_mfma_f32_16x16x32_bf16(afA[f], bf[pg], acc[f][pg], 0, 0, 0);
                    __builtin_amdgcn_s_setprio(0);
                }
                // ---- half 1 (parity 1): compute with afB, prefetch ksc+2 -> afA
                {
                    // ksc+2==18 at the end reads 4KB past this g's slice --
                    // prefetched, never consumed (lands in A3/r1 ws region).
                    PF_AF(afA, ksc + 2);
                    const char* bp = bprow + qv[1][kw];
                    bf16x8 bf[4];
#pragma unroll
                    for (int pg = 0; pg < 4; ++pg)
                        bf[pg] = *(const bf16x8*)(bp + pg * 2048);
                    __builtin_amdgcn_s_setprio(1);
#pragma unroll
                    for (int f = 0; f < 4; ++f)
#pragma unroll
                        for (int pg = 0; pg < 4; ++pg)
                            acc[f][pg] = __builtin_amdgcn_mfma_f32_16x16x32_bf16(afB[f], bf[pg], acc[f][pg], 0, 0, 0);
                    __builtin_amdgcn_s_setprio(0);
                }
            }
        }

        // epilogue: multiply rows (e) by para[e,p], reduce over e
#pragma unroll
        for (int f = 0; f < 4; ++f) {
            int o = obase + f;
#pragma unroll
            for (int pg = 0; pg < 4; ++pg) {
                float s = acc[f][pg][0] * pvv[pg][0] + acc[f][pg][1] * pvv[pg][1] +
                          acc[f][pg][2] * pvv[pg][2] + acc[f][pg][3] * pvv[pg][3];
                s += __shfl_xor(s, 16);
                s += __shfl_xor(s, 32);
                if (lhi == 0)
                    __builtin_nontemporal_store(s, &po[(size_t)o * P_ + pg * 16 + llo]);
            }
        }
    }
#undef PF_AF
}

extern "C" void kernel_launch(void* const* d_in, const int* in_sizes, int n_in,
                              void* d_out, int out_size, void* d_ws, size_t ws_size,
                              hipStream_t stream) {
    const float* x  = (const float*)d_in[0];
    const float* W  = (const float*)d_in[1];
    const float* pw = (const float*)d_in[2];
    const float* pb = (const float*)d_in[3];
    const float* cw = (const float*)d_in[4];
    const float* cb = (const float*)d_in[5];
    float* out = (float*)d_out;
    char* ws = (char*)d_ws;
    unsigned short* xt = (unsigned short*)(ws + OFF_XT);
    unsigned short* Am = (unsigned short*)(ws + OFF_A);
    float* r1   = (float*)(ws + OFF_R1);
    float* para = (float*)(ws + OFF_PARA);

    hipLaunchKernelGGL(k_prep, dim3(320), dim3(256), 0, stream, x, xt, pw, pb, r1, W, Am);
    hipLaunchKernelGGL(k_pred2, dim3(B_ * P_ / 256), dim3(256), 0, stream, r1, cw, cb, para);
    hipLaunchKernelGGL(k_main, dim3(1024), dim3(256), 0, stream, xt, Am, para, out);
}

// Round 15
// 85.802 us; speedup vs baseline: 1.4378x; 1.2865x over previous
//
#include <hip/hip_runtime.h>

typedef __attribute__((ext_vector_type(8))) short short8;
typedef __attribute__((ext_vector_type(8))) __bf16 bf16x8;
typedef __attribute__((ext_vector_type(4))) float f32x4;

// sizes
#define B_ 4
#define C_ 64
#define H_ 128
#define W_ 128
#define P_ (H_*W_)      // 16384
#define E_ 16

// ws layout (bytes)
#define OFF_XT   0u
#define XT_BYTES (4u*130u*130u*64u*2u)          // 8,652,800
#define OFF_A    8652800u
#define OFF_R1   9832448u

__device__ inline unsigned short f2bf(float f) {
    union { float f; unsigned u; } v; v.f = f;
    unsigned r = v.u + 0x7FFF + ((v.u >> 16) & 1);
    return (unsigned short)(r >> 16);
}

// ---------- merged prep kernel: transpose+pad+conv1x1 (blocks 0..255, 2 rows
// each) and A3 build (blocks 256..319). ----------
__global__ __launch_bounds__(256) void k_prep(const float* __restrict__ x,
                                              unsigned short* __restrict__ xt,
                                              const float* __restrict__ pw,
                                              const float* __restrict__ pb,
                                              float* __restrict__ r1,
                                              const float* __restrict__ Wsrc,
                                              unsigned short* __restrict__ A) {
    __shared__ float smem[9216];
    int t = threadIdx.x;
    if (blockIdx.x < 256) {
        // ---- transpose + pad + conv1x1+relu, two image rows per block ----
        float* lpw = smem;          // [1024]
        float* lpb = smem + 1024;   // [16]
        for (int lin = t; lin < 1024; lin += 256) lpw[lin] = pw[lin];
        if (t < 16) lpb[t] = pb[t];
        __syncthreads();

        int rowid = blockIdx.x * 2 + (t >> 7);
        int b = rowid >> 7, y = rowid & 127;
        int tt = t & 127; // x coordinate

        const float* src = x + (size_t)b * C_ * P_ + y * W_ + tt;
        unsigned short* dst = xt + ((size_t)(b * 130 + y + 1) * 130 + tt + 1) * 64;
        float s[16];
#pragma unroll
        for (int e = 0; e < 16; ++e) s[e] = lpb[e];
#pragma unroll
        for (int i = 0; i < 8; ++i) {
            short8 v;
#pragma unroll
            for (int j = 0; j < 8; ++j) {
                float xv = src[(size_t)(i * 8 + j) * P_];
                v[j] = (short)f2bf(xv);
#pragma unroll
                for (int e = 0; e < 16; ++e) s[e] = fmaf(lpw[e * 64 + i * 8 + j], xv, s[e]);
            }
            ((short8*)dst)[i] = v;
        }
        float* rd = r1 + (size_t)b * 16 * P_ + y * 128 + tt;
#pragma unroll
        for (int e = 0; e < 16; ++e) rd[(size_t)e * P_] = fmaxf(s[e], 0.f);

        short8 z = {0,0,0,0,0,0,0,0};
        if (tt < 16) {
            int col = (tt >> 3) * 129, i = tt & 7;
            unsigned short* bp = xt + ((size_t)(b * 130 + y + 1) * 130 + col) * 64;
            ((short8*)bp)[i] = z;
        }
        if (y == 0 || y == 127) {
            int prow = (y == 0) ? 0 : 129;
            unsigned short* rp = xt + (size_t)(b * 130 + prow) * 130 * 64;
            for (int ci = tt; ci < 1040; ci += 128) ((short8*)rp)[ci] = z;
        }
    } else {
        // ---- A3 build: o = blockIdx - 256 ----
        int o = blockIdx.x - 256;
        const float* src = Wsrc + (size_t)o * 9216; // per o: [j'=c*9+tap][e]
        for (int lin = t; lin < 9216; lin += 256) smem[lin] = src[lin];
        __syncthreads();
        int g = o >> 2, f = o & 3;
        unsigned short* dst = A + ((size_t)g * 72 + f) * 512;
        for (int lin = t; lin < 9216; lin += 256) {
            int ks = lin >> 9, rem = lin & 511;
            int lane = rem >> 3, j = rem & 7;
            int llo = lane & 15, lhi = lane >> 4;
            int col = ks * 32 + lhi * 8 + j;
            int tap = col >> 6, c = col & 63;
            dst[(size_t)ks * 2048 + rem] = f2bf(smem[(c * 9 + tap) * 16 + llo]);
        }
    }
}

// ---------- main fused kernel ----------
// R12's proven body (fragment-linear A3 af double-buffer, acc[4][8], setprio,
// 2-block/CU desync) + fused pred2 prologue: computes para[16][128] for this
// row into LDS from r1 (saves the k_pred2 launch + para round-trip); epilogue
// reads pvv from LDS. LDS = 49,920 (xt) + 9,216 (cw re-laid) + 8,192 (para)
// = 67,328 B -> still 2 blocks/CU.
__global__ __launch_bounds__(256, 2) void k_main(const unsigned short* __restrict__ xt,
                                                 const unsigned short* __restrict__ A,
                                                 const float* __restrict__ r1,
                                                 const float* __restrict__ cw,
                                                 const float* __restrict__ cb,
                                                 float* __restrict__ out) {
    __shared__ unsigned short lds[3 * 130 * 64]; // 49,920 B (xt rows)
    __shared__ float lcw2[2304];                 // cw as [ep][tap][e]
    __shared__ float parald[16 * 128];           // para for this row
    int r = blockIdx.x;
    int xcd = r & 7;
    int yl = r >> 3;            // [0,64)
    int rowid = xcd * 64 + yl;  // contiguous 64-row slab per XCD (A stays L2-resident)
    int b = rowid >> 7, y = rowid & 127;

    int tid = threadIdx.x;
    int wave = tid >> 6, lane = tid & 63, lhi = lane >> 4, llo = lane & 15;

    // stage 3 padded xt rows (y..y+2), swizzle byte ^= ((xx&7)<<4)
    const unsigned short* xrow = xt + (size_t)(b * 130 + y) * 130 * 64;
    for (int ci = tid; ci < 3120; ci += 256) {
        int row = ci / 1040, rem = ci - row * 1040;
        int xx = rem >> 3, cc = rem & 7;
        short8 v = *(const short8*)(xrow + ((size_t)row * 130 + xx) * 64 + cc * 8);
        int lb = row * 16640 + xx * 128 + ((cc * 16) ^ ((xx & 7) << 4));
        *(short8*)((char*)lds + lb) = v;
    }
    // stage cw re-laid: lcw2[(ep*9+tap)*16 + e] = cw[(e*16+ep)*9 + tap]
    for (int lin = tid; lin < 2304; lin += 256) {
        int ep = lin / 144, rem = lin - ep * 144;
        int tap = rem >> 4, e = rem & 15;
        lcw2[lin] = cw[(e * 16 + ep) * 9 + tap];
    }
    __syncthreads();

    // ---- fused pred2: para[e][px] for row y, 2 threads/px (8 e's each) ----
    {
        int px = tid & 127, eg = tid >> 7;
        const float* r1b = r1 + (size_t)b * 16 * P_;
        float s[8];
#pragma unroll
        for (int ee = 0; ee < 8; ++ee) s[ee] = cb[eg * 8 + ee];
        for (int dy = 0; dy < 3; ++dy) {
            int yy = y + dy - 1;
            if (yy < 0 || yy > 127) continue;
            for (int dx = 0; dx < 3; ++dx) {
                int xx = px + dx - 1;
                if (xx < 0 || xx > 127) continue;
                int tap = dy * 3 + dx;
                const float* rq = r1b + yy * 128 + xx;
                const float* cwt = lcw2 + tap * 16 + eg * 8;
#pragma unroll
                for (int ep = 0; ep < 16; ++ep) {
                    float v = rq[(size_t)ep * P_];
                    const float* cc = cwt + ep * 144;
#pragma unroll
                    for (int ee = 0; ee < 8; ++ee) s[ee] = fmaf(cc[ee], v, s[ee]);
                }
            }
        }
#pragma unroll
        for (int ee = 0; ee < 8; ++ee) parald[(eg * 8 + ee) * 128 + px] = s[ee];
    }
    __syncthreads();

    float* po = out + (size_t)b * 64 * P_ + y * 128;

    // precomputed LDS read vaddrs: qv[parity][kw]; full addr = qv + kh*16640 + pg*2048
    int qv[2][3];
#pragma unroll
    for (int kw = 0; kw < 3; ++kw) {
        int rowi = llo + kw;
        int base0 = rowi * 128 + ((lhi * 16) ^ ((rowi & 7) << 4));
        qv[0][kw] = base0;
        qv[1][kw] = base0 ^ 64;
    }
    const char* ldsc = (const char*)lds;

#define PF_AF(dst, KS) do { \
    _Pragma("unroll") \
    for (int f_ = 0; f_ < 4; ++f_) \
        dst[f_] = *(const bf16x8*)(Agl + (KS) * 2048 + f_ * 512); \
    __builtin_amdgcn_sched_barrier(0); \
} while (0)

#pragma unroll 1
    for (int chunk = 0; chunk < 4; ++chunk) {
        int obase = chunk * 16 + wave * 4;
        int g = obase >> 2; // o-group index into A3 (= chunk*4 + wave)
        const unsigned short* Agl = A + (size_t)g * 36864 + lane * 8;

        f32x4 acc[4][8];
#pragma unroll
        for (int f = 0; f < 4; ++f)
#pragma unroll
            for (int pg = 0; pg < 8; ++pg) acc[f][pg] = (f32x4){0.f, 0.f, 0.f, 0.f};

        bf16x8 afA[4], afB[4];
        // prologue: A-frags for ks=0
        PF_AF(afA, 0);

#pragma unroll 1
        for (int kh = 0; kh < 3; ++kh) {
#pragma unroll 1
            for (int kw = 0; kw < 3; ++kw) {
                const int ksc = kh * 6 + kw * 2; // current even ks
                const char* bprow = ldsc + kh * 16640;
                // ---- half 0 (parity 0): compute with afA, prefetch ksc+1 -> afB
                {
                    PF_AF(afB, ksc + 1);
                    const char* bp = bprow + qv[0][kw];
                    bf16x8 bf[8];
#pragma unroll
                    for (int pg = 0; pg < 8; ++pg)
                        bf[pg] = *(const bf16x8*)(bp + pg * 2048);
                    __builtin_amdgcn_s_setprio(1);
#pragma unroll
                    for (int f = 0; f < 4; ++f)
#pragma unroll
                        for (int pg = 0; pg < 8; ++pg)
                            acc[f][pg] = __builtin_amdgcn_mfma_f32_16x16x32_bf16(afA[f], bf[pg], acc[f][pg], 0, 0, 0);
                    __builtin_amdgcn_s_setprio(0);
                }
                // ---- half 1 (parity 1): compute with afB, prefetch ksc+2 -> afA
                {
                    // ksc+2==18 at the end reads 4KB past this g's slice --
                    // prefetched, never consumed (lands in ws A3/r1 region).
                    PF_AF(afA, ksc + 2);
                    const char* bp = bprow + qv[1][kw];
                    bf16x8 bf[8];
#pragma unroll
                    for (int pg = 0; pg < 8; ++pg)
                        bf[pg] = *(const bf16x8*)(bp + pg * 2048);
                    __builtin_amdgcn_s_setprio(1);
#pragma unroll
                    for (int f = 0; f < 4; ++f)
#pragma unroll
                        for (int pg = 0; pg < 8; ++pg)
                            acc[f][pg] = __builtin_amdgcn_mfma_f32_16x16x32_bf16(afB[f], bf[pg], acc[f][pg], 0, 0, 0);
                    __builtin_amdgcn_s_setprio(0);
                }
            }
        }

        // epilogue: multiply rows (e) by para[e,p] (from LDS), reduce over e
        float pvv[8][4];
#pragma unroll
        for (int pg = 0; pg < 8; ++pg)
#pragma unroll
            for (int rr = 0; rr < 4; ++rr)
                pvv[pg][rr] = parald[(lhi * 4 + rr) * 128 + pg * 16 + llo];

#pragma unroll
        for (int f = 0; f < 4; ++f) {
            int o = obase + f;
#pragma unroll
            for (int pg = 0; pg < 8; ++pg) {
                float s = acc[f][pg][0] * pvv[pg][0] + acc[f][pg][1] * pvv[pg][1] +
                          acc[f][pg][2] * pvv[pg][2] + acc[f][pg][3] * pvv[pg][3];
                s += __shfl_xor(s, 16);
                s += __shfl_xor(s, 32);
                if (lhi == 0)
                    __builtin_nontemporal_store(s, &po[(size_t)o * P_ + pg * 16 + llo]);
            }
        }
    }
#undef PF_AF
}

extern "C" void kernel_launch(void* const* d_in, const int* in_sizes, int n_in,
                              void* d_out, int out_size, void* d_ws, size_t ws_size,
                              hipStream_t stream) {
    const float* x  = (const float*)d_in[0];
    const float* W  = (const float*)d_in[1];
    const float* pw = (const float*)d_in[2];
    const float* pb = (const float*)d_in[3];
    const float* cw = (const float*)d_in[4];
    const float* cb = (const float*)d_in[5];
    float* out = (float*)d_out;
    char* ws = (char*)d_ws;
    unsigned short* xt = (unsigned short*)(ws + OFF_XT);
    unsigned short* Am = (unsigned short*)(ws + OFF_A);
    float* r1   = (float*)(ws + OFF_R1);

    hipLaunchKernelGGL(k_prep, dim3(320), dim3(256), 0, stream, x, xt, pw, pb, r1, W, Am);
    hipLaunchKernelGGL(k_main, dim3(512), dim3(256), 0, stream, xt, Am, r1, cw, cb, out);
}

// Round 16
// 85.459 us; speedup vs baseline: 1.4435x; 1.0040x over previous
//
#include <hip/hip_runtime.h>

typedef __attribute__((ext_vector_type(8))) short short8;
typedef __attribute__((ext_vector_type(8))) __bf16 bf16x8;
typedef __attribute__((ext_vector_type(4))) float f32x4;

// sizes
#define B_ 4
#define C_ 64
#define H_ 128
#define W_ 128
#define P_ (H_*W_)      // 16384
#define E_ 16

// ws layout (bytes)
#define OFF_XT   0u
#define XT_BYTES (4u*130u*130u*64u*2u)          // 8,652,800
#define OFF_A    8652800u
#define OFF_R1   9832448u

__device__ inline unsigned short f2bf(float f) {
    union { float f; unsigned u; } v; v.f = f;
    unsigned r = v.u + 0x7FFF + ((v.u >> 16) & 1);
    return (unsigned short)(r >> 16);
}

// ---------- merged prep kernel: transpose+pad+conv1x1 (blocks 0..255, 2 rows
// each) and A3 build (blocks 256..319). ----------
__global__ __launch_bounds__(256) void k_prep(const float* __restrict__ x,
                                              unsigned short* __restrict__ xt,
                                              const float* __restrict__ pw,
                                              const float* __restrict__ pb,
                                              float* __restrict__ r1,
                                              const float* __restrict__ Wsrc,
                                              unsigned short* __restrict__ A) {
    __shared__ float smem[9216];
    int t = threadIdx.x;
    if (blockIdx.x < 256) {
        // ---- transpose + pad + conv1x1+relu, two image rows per block ----
        float* lpw = smem;          // [1024]
        float* lpb = smem + 1024;   // [16]
        for (int lin = t; lin < 1024; lin += 256) lpw[lin] = pw[lin];
        if (t < 16) lpb[t] = pb[t];
        __syncthreads();

        int rowid = blockIdx.x * 2 + (t >> 7);
        int b = rowid >> 7, y = rowid & 127;
        int tt = t & 127; // x coordinate

        const float* src = x + (size_t)b * C_ * P_ + y * W_ + tt;
        unsigned short* dst = xt + ((size_t)(b * 130 + y + 1) * 130 + tt + 1) * 64;
        float s[16];
#pragma unroll
        for (int e = 0; e < 16; ++e) s[e] = lpb[e];
#pragma unroll
        for (int i = 0; i < 8; ++i) {
            short8 v;
#pragma unroll
            for (int j = 0; j < 8; ++j) {
                float xv = src[(size_t)(i * 8 + j) * P_];
                v[j] = (short)f2bf(xv);
#pragma unroll
                for (int e = 0; e < 16; ++e) s[e] = fmaf(lpw[e * 64 + i * 8 + j], xv, s[e]);
            }
            ((short8*)dst)[i] = v;
        }
        float* rd = r1 + (size_t)b * 16 * P_ + y * 128 + tt;
#pragma unroll
        for (int e = 0; e < 16; ++e) rd[(size_t)e * P_] = fmaxf(s[e], 0.f);

        short8 z = {0,0,0,0,0,0,0,0};
        if (tt < 16) {
            int col = (tt >> 3) * 129, i = tt & 7;
            unsigned short* bp = xt + ((size_t)(b * 130 + y + 1) * 130 + col) * 64;
            ((short8*)bp)[i] = z;
        }
        if (y == 0 || y == 127) {
            int prow = (y == 0) ? 0 : 129;
            unsigned short* rp = xt + (size_t)(b * 130 + prow) * 130 * 64;
            for (int ci = tt; ci < 1040; ci += 128) ((short8*)rp)[ci] = z;
        }
    } else {
        // ---- A3 build: o = blockIdx - 256 ----
        int o = blockIdx.x - 256;
        const float* src = Wsrc + (size_t)o * 9216; // per o: [j'=c*9+tap][e]
        for (int lin = t; lin < 9216; lin += 256) smem[lin] = src[lin];
        __syncthreads();
        int g = o >> 2, f = o & 3;
        unsigned short* dst = A + ((size_t)g * 72 + f) * 512;
        for (int lin = t; lin < 9216; lin += 256) {
            int ks = lin >> 9, rem = lin & 511;
            int lane = rem >> 3, j = rem & 7;
            int llo = lane & 15, lhi = lane >> 4;
            int col = ks * 32 + lhi * 8 + j;
            int tap = col >> 6, c = col & 63;
            dst[(size_t)ks * 2048 + rem] = f2bf(smem[(c * 9 + tap) * 16 + llo]);
        }
    }
}

// ---------- main fused kernel ----------
// R15 structure (fused pred2 prologue, fragment-linear A3, acc[4][8],
// setprio, 2 blocks/CU) + R16 change: af TRIPLE buffer (afA/B/C, static
// period-3 rotation, 6 halves per kh = 2 periods) -> prefetch distance 2
// half-bodies (~1240 cy) covers af L2-miss latency that distance-1 exposed.
__global__ __launch_bounds__(256, 2) void k_main(const unsigned short* __restrict__ xt,
                                                 const unsigned short* __restrict__ A,
                                                 const float* __restrict__ r1,
                                                 const float* __restrict__ cw,
                                                 const float* __restrict__ cb,
                                                 float* __restrict__ out) {
    __shared__ unsigned short lds[3 * 130 * 64]; // 49,920 B (xt rows)
    __shared__ float lcw2[2304];                 // cw as [ep][tap][e]
    __shared__ float parald[16 * 128];           // para for this row
    int r = blockIdx.x;
    int xcd = r & 7;
    int yl = r >> 3;            // [0,64)
    int rowid = xcd * 64 + yl;  // contiguous 64-row slab per XCD (A stays L2-resident)
    int b = rowid >> 7, y = rowid & 127;

    int tid = threadIdx.x;
    int wave = tid >> 6, lane = tid & 63, lhi = lane >> 4, llo = lane & 15;

    // stage 3 padded xt rows (y..y+2), swizzle byte ^= ((xx&7)<<4)
    const unsigned short* xrow = xt + (size_t)(b * 130 + y) * 130 * 64;
    for (int ci = tid; ci < 3120; ci += 256) {
        int row = ci / 1040, rem = ci - row * 1040;
        int xx = rem >> 3, cc = rem & 7;
        short8 v = *(const short8*)(xrow + ((size_t)row * 130 + xx) * 64 + cc * 8);
        int lb = row * 16640 + xx * 128 + ((cc * 16) ^ ((xx & 7) << 4));
        *(short8*)((char*)lds + lb) = v;
    }
    // stage cw re-laid: lcw2[(ep*9+tap)*16 + e] = cw[(e*16+ep)*9 + tap]
    for (int lin = tid; lin < 2304; lin += 256) {
        int ep = lin / 144, rem = lin - ep * 144;
        int tap = rem >> 4, e = rem & 15;
        lcw2[lin] = cw[(e * 16 + ep) * 9 + tap];
    }
    __syncthreads();

    // ---- fused pred2: para[e][px] for row y, 2 threads/px (8 e's each) ----
    {
        int px = tid & 127, eg = tid >> 7;
        const float* r1b = r1 + (size_t)b * 16 * P_;
        float s[8];
#pragma unroll
        for (int ee = 0; ee < 8; ++ee) s[ee] = cb[eg * 8 + ee];
        for (int dy = 0; dy < 3; ++dy) {
            int yy = y + dy - 1;
            if (yy < 0 || yy > 127) continue;
            for (int dx = 0; dx < 3; ++dx) {
                int xx = px + dx - 1;
                if (xx < 0 || xx > 127) continue;
                int tap = dy * 3 + dx;
                const float* rq = r1b + yy * 128 + xx;
                const float* cwt = lcw2 + tap * 16 + eg * 8;
#pragma unroll
                for (int ep = 0; ep < 16; ++ep) {
                    float v = rq[(size_t)ep * P_];
                    const float* cc = cwt + ep * 144;
#pragma unroll
                    for (int ee = 0; ee < 8; ++ee) s[ee] = fmaf(cc[ee], v, s[ee]);
                }
            }
        }
#pragma unroll
        for (int ee = 0; ee < 8; ++ee) parald[(eg * 8 + ee) * 128 + px] = s[ee];
    }
    __syncthreads();

    float* po = out + (size_t)b * 64 * P_ + y * 128;

    // precomputed LDS read vaddrs: qv[parity][kw]; full addr = qv + kh*16640 + pg*2048
    int qv[2][3];
#pragma unroll
    for (int kw = 0; kw < 3; ++kw) {
        int rowi = llo + kw;
        int base0 = rowi * 128 + ((lhi * 16) ^ ((rowi & 7) << 4));
        qv[0][kw] = base0;
        qv[1][kw] = base0 ^ 64;
    }
    const char* ldsc = (const char*)lds;

#define PF_AF(dst, KS) do { \
    _Pragma("unroll") \
    for (int f_ = 0; f_ < 4; ++f_) \
        dst[f_] = *(const bf16x8*)(Agl + (KS) * 2048 + f_ * 512); \
    __builtin_amdgcn_sched_barrier(0); \
} while (0)

// one half-body: prefetch A for PFKS into AFP (distance 2), compute with AFU
#define HALF(AFU, AFP, PFKS, PAR, KW) do { \
    PF_AF(AFP, PFKS); \
    const char* bp = bprow + qv[PAR][KW]; \
    bf16x8 bf[8]; \
    _Pragma("unroll") \
    for (int pg_ = 0; pg_ < 8; ++pg_) \
        bf[pg_] = *(const bf16x8*)(bp + pg_ * 2048); \
    __builtin_amdgcn_s_setprio(1); \
    _Pragma("unroll") \
    for (int f_ = 0; f_ < 4; ++f_) \
    _Pragma("unroll") \
    for (int pg_ = 0; pg_ < 8; ++pg_) \
        acc[f_][pg_] = __builtin_amdgcn_mfma_f32_16x16x32_bf16(AFU[f_], bf[pg_], acc[f_][pg_], 0, 0, 0); \
    __builtin_amdgcn_s_setprio(0); \
} while (0)

#pragma unroll 1
    for (int chunk = 0; chunk < 4; ++chunk) {
        int obase = chunk * 16 + wave * 4;
        int g = obase >> 2; // o-group index into A3 (= chunk*4 + wave)
        const unsigned short* Agl = A + (size_t)g * 36864 + lane * 8;

        f32x4 acc[4][8];
#pragma unroll
        for (int f = 0; f < 4; ++f)
#pragma unroll
            for (int pg = 0; pg < 8; ++pg) acc[f][pg] = (f32x4){0.f, 0.f, 0.f, 0.f};

        bf16x8 afA[4], afB[4], afC[4];
        // prologue: A-frags for ks=0,1 (distance-2 pipeline fill)
        PF_AF(afA, 0);
        PF_AF(afB, 1);

#pragma unroll 1
        for (int kh = 0; kh < 3; ++kh) {
            const int ksc = kh * 6;
            const char* bprow = ldsc + kh * 16640;
            // 6 halves per kh = 2 period-3 buffer rotations.
            // ks -> (par,kw): ks = ksc + kw*2 + par; buffer = ks % 3.
            // kh=2 prefetches ks 18,19: overread into ws A-region padding,
            // never consumed (next chunk re-fills the pipeline).
            HALF(afA, afC, ksc + 2, 0, 0);
            HALF(afB, afA, ksc + 3, 1, 0);
            HALF(afC, afB, ksc + 4, 0, 1);
            HALF(afA, afC, ksc + 5, 1, 1);
            HALF(afB, afA, ksc + 6, 0, 2);
            HALF(afC, afB, ksc + 7, 1, 2);
        }

        // epilogue: multiply rows (e) by para[e,p] (from LDS), reduce over e
        float pvv[8][4];
#pragma unroll
        for (int pg = 0; pg < 8; ++pg)
#pragma unroll
            for (int rr = 0; rr < 4; ++rr)
                pvv[pg][rr] = parald[(lhi * 4 + rr) * 128 + pg * 16 + llo];

#pragma unroll
        for (int f = 0; f < 4; ++f) {
            int o = obase + f;
#pragma unroll
            for (int pg = 0; pg < 8; ++pg) {
                float s = acc[f][pg][0] * pvv[pg][0] + acc[f][pg][1] * pvv[pg][1] +
                          acc[f][pg][2] * pvv[pg][2] + acc[f][pg][3] * pvv[pg][3];
                s += __shfl_xor(s, 16);
                s += __shfl_xor(s, 32);
                if (lhi == 0)
                    __builtin_nontemporal_store(s, &po[(size_t)o * P_ + pg * 16 + llo]);
            }
        }
    }
#undef PF_AF
#undef HALF
}

extern "C" void kernel_launch(void* const* d_in, const int* in_sizes, int n_in,
                              void* d_out, int out_size, void* d_ws, size_t ws_size,
                              hipStream_t stream) {
    const float* x  = (const float*)d_in[0];
    const float* W  = (const float*)d_in[1];
    const float* pw = (const float*)d_in[2];
    const float* pb = (const float*)d_in[3];
    const float* cw = (const float*)d_in[4];
    const float* cb = (const float*)d_in[5];
    float* out = (float*)d_out;
    char* ws = (char*)d_ws;
    unsigned short* xt = (unsigned short*)(ws + OFF_XT);
    unsigned short* Am = (unsigned short*)(ws + OFF_A);
    float* r1   = (float*)(ws + OFF_R1);

    hipLaunchKernelGGL(k_prep, dim3(320), dim3(256), 0, stream, x, xt, pw, pb, r1, W, Am);
    hipLaunchKernelGGL(k_main, dim3(512), dim3(256), 0, stream, xt, Am, r1, cw, cb, out);
}